// Round 1
// baseline (452.379 us; speedup 1.0000x reference)
//
#include <hip/hip_runtime.h>

typedef unsigned short u16;
typedef __bf16 bf16x8_t __attribute__((ext_vector_type(8)));
typedef float f32x4_t __attribute__((ext_vector_type(4)));
typedef short s16x8_t __attribute__((ext_vector_type(8)));

__device__ __forceinline__ u16 f2bf(float f) {
  unsigned u = __builtin_bit_cast(unsigned, f);
  u += 0x7FFFu + ((u >> 16) & 1u);   // round-to-nearest-even
  return (u16)(u >> 16);
}
__device__ __forceinline__ float bf2f(u16 h) {
  unsigned u = ((unsigned)h) << 16;
  return __builtin_bit_cast(float, u);
}

// ---------------- cast the 4 weight matrices fp32->bf16 (each 524288 elems) ---
__global__ __launch_bounds__(256) void cast4_kernel(
    const float* __restrict__ a0, const float* __restrict__ a1,
    const float* __restrict__ a2, const float* __restrict__ a3,
    u16* __restrict__ out) {
  const int z = blockIdx.z;
  const float* a = (z == 0) ? a0 : (z == 1) ? a1 : (z == 2) ? a2 : a3;
  const int i = blockIdx.x * 256 + threadIdx.x;
  out[(size_t)z * 524288 + i] = f2bf(a[i]);
}

// ---------------- fp32 [R,C] -> bf16 [C,R] (batched) --------------------------
__global__ __launch_bounds__(256) void cast_transpose_kernel(
    const float* __restrict__ in, u16* __restrict__ out,
    int R, int C, long sIn, long sOut) {
  __shared__ u16 t[32][33];
  const int b = blockIdx.z;
  in += (long)b * sIn;
  out += (long)b * sOut;
  const int c0 = blockIdx.x * 32, r0 = blockIdx.y * 32;
  const int tx = threadIdx.x, ty = threadIdx.y;
#pragma unroll
  for (int i = 0; i < 32; i += 8)
    t[ty + i][tx] = f2bf(in[(long)(r0 + ty + i) * C + c0 + tx]);
  __syncthreads();
#pragma unroll
  for (int i = 0; i < 32; i += 8)
    out[(long)(c0 + ty + i) * R + r0 + tx] = t[tx][ty + i];
}

// ---------------- bf16 [R,C] -> bf16 [C,R] (batched) --------------------------
__global__ __launch_bounds__(256) void transpose_kernel(
    const u16* __restrict__ in, u16* __restrict__ out,
    int R, int C, long sIn, long sOut) {
  __shared__ u16 t[32][33];
  const int b = blockIdx.z;
  in += (long)b * sIn;
  out += (long)b * sOut;
  const int c0 = blockIdx.x * 32, r0 = blockIdx.y * 32;
  const int tx = threadIdx.x, ty = threadIdx.y;
#pragma unroll
  for (int i = 0; i < 32; i += 8)
    t[ty + i][tx] = in[(long)(r0 + ty + i) * C + c0 + tx];
  __syncthreads();
#pragma unroll
  for (int i = 0; i < 32; i += 8)
    out[(long)(c0 + ty + i) * R + r0 + tx] = t[tx][ty + i];
}

// ---------------- bf16 GEMM: C[M,N] = A[M,K] * Bt[N,K]^T  ---------------------
// A, Bt row-major bf16 (K contiguous). 128x128 tile, BK=32, 4 waves, 4x4 frags.
// mfma_f32_16x16x32_bf16: A-frag a[j]=A[l&15][(l>>4)*8+j]; B-frag b[j]=B[(l>>4)*8+j][l&15];
// D: reg r -> D[(l>>4)*4+r][l&15]   (layouts per CDNA4 guide, HW-verified C/D map)
template <bool OUTBF16, bool BIAS, bool RESID>
__global__ __launch_bounds__(256) void gemm_bt(
    const u16* __restrict__ A, int lda, long sA,
    const u16* __restrict__ B, int ldb, long sB,
    void* __restrict__ C, int ldc, long sC,
    const float* __restrict__ bias,
    const float* __restrict__ resid, long sR, int K) {
  __shared__ alignas(16) u16 As[128][40];  // +8 pad kills bank conflicts
  __shared__ alignas(16) u16 Bs[128][40];

  const int tid = threadIdx.x;
  const int bz = blockIdx.z;
  const long rowbase = (long)blockIdx.y * 128;
  const long colbase = (long)blockIdx.x * 128;

  const int srow = tid >> 2;          // 0..63
  const int skof = (tid & 3) * 8;     // 0,8,16,24
  const u16* Ab = A + (long)bz * sA + (rowbase + srow) * (long)lda + skof;
  const u16* Bb = B + (long)bz * sB + (colbase + srow) * (long)ldb + skof;

  const int lane = tid & 63, wave = tid >> 6;
  const int wr = (wave >> 1) * 64, wc = (wave & 1) * 64;
  const int l15 = lane & 15, lhi = lane >> 4;

  f32x4_t acc[4][4] = {};

  for (int k0 = 0; k0 < K; k0 += 32) {
    s16x8_t a0 = *(const s16x8_t*)(Ab);
    s16x8_t a1 = *(const s16x8_t*)(Ab + (long)64 * lda);
    s16x8_t b0 = *(const s16x8_t*)(Bb);
    s16x8_t b1 = *(const s16x8_t*)(Bb + (long)64 * ldb);
    Ab += 32;
    Bb += 32;
    __syncthreads();  // previous iter's LDS reads must finish
    *(s16x8_t*)&As[srow][skof] = a0;
    *(s16x8_t*)&As[srow + 64][skof] = a1;
    *(s16x8_t*)&Bs[srow][skof] = b0;
    *(s16x8_t*)&Bs[srow + 64][skof] = b1;
    __syncthreads();
    bf16x8_t af[4], bfr[4];
#pragma unroll
    for (int m = 0; m < 4; m++)
      af[m] = *(const bf16x8_t*)&As[wr + m * 16 + l15][lhi * 8];
#pragma unroll
    for (int n = 0; n < 4; n++)
      bfr[n] = *(const bf16x8_t*)&Bs[wc + n * 16 + l15][lhi * 8];
#pragma unroll
    for (int m = 0; m < 4; m++)
#pragma unroll
      for (int n = 0; n < 4; n++)
        acc[m][n] = __builtin_amdgcn_mfma_f32_16x16x32_bf16(af[m], bfr[n],
                                                            acc[m][n], 0, 0, 0);
  }

  const long cb = (long)bz * sC;
#pragma unroll
  for (int m = 0; m < 4; m++) {
#pragma unroll
    for (int r = 0; r < 4; r++) {
      const long row = rowbase + wr + m * 16 + lhi * 4 + r;
      const float bv = BIAS ? bias[row] : 0.0f;
#pragma unroll
      for (int n = 0; n < 4; n++) {
        const long col = colbase + wc + n * 16 + l15;
        float v = acc[m][n][r] + bv;
        if (RESID) v += resid[(long)bz * sR + row * ldc + col];
        if (OUTBF16)
          ((u16*)C)[cb + row * ldc + col] = f2bf(v);
        else
          ((float*)C)[cb + row * ldc + col] = v;
      }
    }
  }
}

// ---------------- row softmax over 2304 elems; writes bf16 P in place ---------
// INF32: rows are fp32 (stride 2304 floats); bf16 P written over the row start
// (P row n then lives at u16-offset n*4608, i.e. lda=4608 for the PV GEMM).
template <bool INF32>
__global__ __launch_bounds__(256) void softmax_kernel(void* __restrict__ att) {
  __shared__ float red[8];
  const long rowi = (long)blockIdx.y * 2304 + blockIdx.x;
  const int tid = threadIdx.x;
  float v[9];
  if (INF32) {
    const float* p = (const float*)att + rowi * 2304;
#pragma unroll
    for (int j = 0; j < 9; j++) v[j] = p[tid + j * 256];
  } else {
    const u16* p = (const u16*)att + rowi * 2304;
#pragma unroll
    for (int j = 0; j < 9; j++) v[j] = bf2f(p[tid + j * 256]);
  }
  float m = v[0];
#pragma unroll
  for (int j = 1; j < 9; j++) m = fmaxf(m, v[j]);
#pragma unroll
  for (int o = 32; o; o >>= 1) m = fmaxf(m, __shfl_xor(m, o));
  if ((tid & 63) == 0) red[tid >> 6] = m;
  __syncthreads();
  m = fmaxf(fmaxf(red[0], red[1]), fmaxf(red[2], red[3]));
  float s = 0.0f;
#pragma unroll
  for (int j = 0; j < 9; j++) {
    v[j] = expf(v[j] - m);
    s += v[j];
  }
#pragma unroll
  for (int o = 32; o; o >>= 1) s += __shfl_xor(s, o);
  __syncthreads();
  if ((tid & 63) == 0) red[4 + (tid >> 6)] = s;
  __syncthreads();
  s = (red[4] + red[5]) + (red[6] + red[7]);
  const float inv = 1.0f / s;
  u16* q = INF32 ? (u16*)((const float*)att + rowi * 2304)
                 : (u16*)att + rowi * 2304;
#pragma unroll
  for (int j = 0; j < 9; j++) q[tid + j * 256] = f2bf(v[j] * inv);
}

extern "C" void kernel_launch(void* const* d_in, const int* in_sizes, int n_in,
                              void* d_out, int out_size, void* d_ws,
                              size_t ws_size, hipStream_t stream) {
  const float* x = (const float*)d_in[0];
  const float* w1 = (const float*)d_in[1];
  const float* b1 = (const float*)d_in[2];
  const float* w2 = (const float*)d_in[3];
  const float* b2 = (const float*)d_in[4];
  const float* w3 = (const float*)d_in[5];
  const float* b3 = (const float*)d_in[6];
  const float* w4 = (const float*)d_in[7];
  const float* b4 = (const float*)d_in[8];
  float* out = (float*)d_out;
  char* ws = (char*)d_ws;

  // B=8, HW=2304, CIN=1024, CMID=512
  // ws layout: region0 = [xT 37.75M | phi_nat 18.87M | g_nat 18.87M] overlaid
  // later by att (fp32 169.87M or bf16 84.93M); then wb(4M), theta, phiT, gT,
  // y, yrT (18.87M each).
  const size_t ATT_F32 = 169869312ull, ATT_BF16 = 84934656ull;
  const size_t TAIL = 4194304ull + 5ull * 18874368ull;  // 98566144
  const bool attF32 = (ws_size >= ATT_F32 + TAIL);      // 256 MiB exactly
  if (!attF32 && ws_size < ATT_BF16 + TAIL) return;     // can't run
  const size_t attRegion = attF32 ? ATT_F32 : ATT_BF16;

  u16* p_xT = (u16*)(ws);
  u16* p_phin = (u16*)(ws + 37748736);
  u16* p_gn = (u16*)(ws + 56623104);
  void* p_att = (void*)ws;
  u16* p_wb = (u16*)(ws + attRegion);
  u16* p_theta = (u16*)(ws + attRegion + 4194304);
  u16* p_phiT = (u16*)(ws + attRegion + 4194304 + 1ull * 18874368);
  u16* p_gT = (u16*)(ws + attRegion + 4194304 + 2ull * 18874368);
  u16* p_y = (u16*)(ws + attRegion + 4194304 + 3ull * 18874368);
  u16* p_yrT = (u16*)(ws + attRegion + 4194304 + 4ull * 18874368);

  // 1) weights -> bf16
  cast4_kernel<<<dim3(2048, 1, 4), 256, 0, stream>>>(w1, w2, w3, w4, p_wb);
  // 2) xT[b] = cast(x[b])^T : [1024,2304] -> [2304,1024]
  cast_transpose_kernel<<<dim3(72, 32, 8), dim3(32, 8), 0, stream>>>(
      x, p_xT, 1024, 2304, 2359296L, 2359296L);
  // 3) theta/phi/g convs: M=512,N=2304,K=1024 (A=w, Bt=xT)
  gemm_bt<true, true, false><<<dim3(18, 4, 8), 256, 0, stream>>>(
      p_wb, 1024, 0, p_xT, 1024, 2359296L, p_theta, 2304, 1179648L, b1,
      nullptr, 0, 1024);
  gemm_bt<true, true, false><<<dim3(18, 4, 8), 256, 0, stream>>>(
      p_wb + 524288, 1024, 0, p_xT, 1024, 2359296L, p_phin, 2304, 1179648L, b2,
      nullptr, 0, 1024);
  gemm_bt<true, true, false><<<dim3(18, 4, 8), 256, 0, stream>>>(
      p_wb + 1048576, 1024, 0, p_xT, 1024, 2359296L, p_gn, 2304, 1179648L, b3,
      nullptr, 0, 1024);
  // 4) phiT[m,c] = phi_nat[c,m]; gT[c,m] = g_flat viewed [2304,512] transposed
  transpose_kernel<<<dim3(72, 16, 8), dim3(32, 8), 0, stream>>>(
      p_phin, p_phiT, 512, 2304, 1179648L, 1179648L);
  transpose_kernel<<<dim3(16, 72, 8), dim3(32, 8), 0, stream>>>(
      p_gn, p_gT, 2304, 512, 1179648L, 1179648L);
  // 5) scores + softmax + PV
  if (attF32) {
    gemm_bt<false, false, false><<<dim3(18, 18, 8), 256, 0, stream>>>(
        p_theta, 512, 1179648L, p_phiT, 512, 1179648L, p_att, 2304, 5308416L,
        nullptr, nullptr, 0, 512);
    softmax_kernel<true><<<dim3(2304, 8), 256, 0, stream>>>(p_att);
    gemm_bt<true, false, false><<<dim3(4, 18, 8), 256, 0, stream>>>(
        (const u16*)p_att, 4608, 10616832L, p_gT, 2304, 1179648L, p_y, 512,
        1179648L, nullptr, nullptr, 0, 2304);
  } else {
    gemm_bt<true, false, false><<<dim3(18, 18, 8), 256, 0, stream>>>(
        p_theta, 512, 1179648L, p_phiT, 512, 1179648L, p_att, 2304, 5308416L,
        nullptr, nullptr, 0, 512);
    softmax_kernel<false><<<dim3(2304, 8), 256, 0, stream>>>(p_att);
    gemm_bt<true, false, false><<<dim3(4, 18, 8), 256, 0, stream>>>(
        (const u16*)p_att, 2304, 5308416L, p_gT, 2304, 1179648L, p_y, 512,
        1179648L, nullptr, nullptr, 0, 2304);
  }
  // 6) y viewed [512,2304] -> yrT [2304,512]
  transpose_kernel<<<dim3(72, 16, 8), dim3(32, 8), 0, stream>>>(
      p_y, p_yrT, 512, 2304, 1179648L, 1179648L);
  // 7) out = x + w4 @ y_r + b4 : M=1024,N=2304,K=512
  gemm_bt<false, true, true><<<dim3(18, 8, 8), 256, 0, stream>>>(
      p_wb + 1572864, 512, 0, p_yrT, 512, 1179648L, out, 2304, 2359296L, b4, x,
      2359296L, 512);
}

// Round 2
// 422.243 us; speedup vs baseline: 1.0714x; 1.0714x over previous
//
#include <hip/hip_runtime.h>

typedef unsigned short u16;
typedef __bf16 bf16x8_t __attribute__((ext_vector_type(8)));
typedef float f32x4_t __attribute__((ext_vector_type(4)));

__device__ __forceinline__ u16 f2bf(float f) {
  unsigned u = __builtin_bit_cast(unsigned, f);
  u += 0x7FFFu + ((u >> 16) & 1u);   // round-to-nearest-even
  return (u16)(u >> 16);
}
__device__ __forceinline__ float bf2f(u16 h) {
  unsigned u = ((unsigned)h) << 16;
  return __builtin_bit_cast(float, u);
}

typedef __attribute__((address_space(1))) const unsigned gas_u32;
typedef __attribute__((address_space(3))) unsigned las_u32;
__device__ __forceinline__ void gload16(const void* g, void* l) {
  // async global->LDS, 16B/lane; LDS dest = wave-uniform base + lane*16
  __builtin_amdgcn_global_load_lds((gas_u32*)g, (las_u32*)l, 16, 0, 0);
}

// ---------------- cast the 4 weight matrices fp32->bf16 (each 524288 elems) ---
__global__ __launch_bounds__(256) void cast4_kernel(
    const float* __restrict__ a0, const float* __restrict__ a1,
    const float* __restrict__ a2, const float* __restrict__ a3,
    u16* __restrict__ out) {
  const int z = blockIdx.z;
  const float* a = (z == 0) ? a0 : (z == 1) ? a1 : (z == 2) ? a2 : a3;
  const int i = blockIdx.x * 256 + threadIdx.x;
  out[(size_t)z * 524288 + i] = f2bf(a[i]);
}

// ---------------- concat b1,b2,b3 -> [1536] ----------------------------------
__global__ __launch_bounds__(256) void bcat_kernel(
    const float* __restrict__ b1, const float* __restrict__ b2,
    const float* __restrict__ b3, float* __restrict__ o) {
  const int i = blockIdx.x * 256 + threadIdx.x;
  o[i] = (i < 512) ? b1[i] : (i < 1024) ? b2[i - 512] : b3[i - 1024];
}

// ---------------- fp32 [R,C] -> bf16 [C,R] (batched) --------------------------
__global__ __launch_bounds__(256) void cast_transpose_kernel(
    const float* __restrict__ in, u16* __restrict__ out,
    int R, int C, long sIn, long sOut) {
  __shared__ u16 t[32][33];
  const int b = blockIdx.z;
  in += (long)b * sIn;
  out += (long)b * sOut;
  const int c0 = blockIdx.x * 32, r0 = blockIdx.y * 32;
  const int tx = threadIdx.x, ty = threadIdx.y;
#pragma unroll
  for (int i = 0; i < 32; i += 8)
    t[ty + i][tx] = f2bf(in[(long)(r0 + ty + i) * C + c0 + tx]);
  __syncthreads();
#pragma unroll
  for (int i = 0; i < 32; i += 8)
    out[(long)(c0 + ty + i) * R + r0 + tx] = t[tx][ty + i];
}

// ---------------- bf16 [R,C] -> bf16 [C,R] (batched) --------------------------
__global__ __launch_bounds__(256) void transpose_kernel(
    const u16* __restrict__ in, u16* __restrict__ out,
    int R, int C, long sIn, long sOut) {
  __shared__ u16 t[32][33];
  const int b = blockIdx.z;
  in += (long)b * sIn;
  out += (long)b * sOut;
  const int c0 = blockIdx.x * 32, r0 = blockIdx.y * 32;
  const int tx = threadIdx.x, ty = threadIdx.y;
#pragma unroll
  for (int i = 0; i < 32; i += 8)
    t[ty + i][tx] = in[(long)(r0 + ty + i) * C + c0 + tx];
  __syncthreads();
#pragma unroll
  for (int i = 0; i < 32; i += 8)
    out[(long)(c0 + ty + i) * R + r0 + tx] = t[tx][ty + i];
}

// ---------------- bf16 GEMM, m97 structure: C = A[M,K] * Bt[N,K]^T ------------
// global_load_lds width-16 staging into linear [128][32] LDS tiles, 2-barrier
// loop, 4 waves, 4x4 16x16x32 fragments per wave.
// SPLIT3: M=1536 row-space routed to 3 output tensors of 512 rows each.
template <bool OUTBF16, bool BIAS, bool RESID, bool SPLIT3>
__global__ __launch_bounds__(256) void gemm_glds(
    const u16* __restrict__ A, int lda, long sA,
    const u16* __restrict__ B, int ldb, long sB,
    void* __restrict__ C0, void* __restrict__ C1, void* __restrict__ C2,
    int ldc, long sC,
    const float* __restrict__ bias,
    const float* __restrict__ resid, long sR, int K) {
  __shared__ alignas(16) u16 As[128 * 32];
  __shared__ alignas(16) u16 Bs[128 * 32];

  const int tid = threadIdx.x;
  const int w = tid >> 6, l = tid & 63;
  const int bz = blockIdx.z;
  const int rowbase = blockIdx.y * 128;
  const int colbase = blockIdx.x * 128;

  // staging: load i in {0,1}: rows (w*2+i)*16 + l/4, cols (l&3)*8 .. +8
  const int srow = (w * 2) * 16 + (l >> 2);
  const int scol = (l & 3) * 8;
  const u16* Ap = A + (long)bz * sA + (long)(rowbase + srow) * lda + scol;
  const u16* Bp = B + (long)bz * sB + (long)(colbase + srow) * ldb + scol;
  u16* la0 = As + (w * 2) * 512;       // wave-uniform LDS bases
  u16* la1 = As + (w * 2 + 1) * 512;
  u16* lb0 = Bs + (w * 2) * 512;
  u16* lb1 = Bs + (w * 2 + 1) * 512;
  const long a16 = 16L * lda, b16 = 16L * ldb;

  const int wr = (w >> 1) * 64, wc = (w & 1) * 64;
  const int l15 = l & 15, lhi = l >> 4;

  f32x4_t acc[4][4] = {};

  for (int k0 = 0; k0 < K; k0 += 32) {
    __syncthreads();               // prior iter's ds_reads done before overwrite
    gload16(Ap, la0);
    gload16(Ap + a16, la1);
    gload16(Bp, lb0);
    gload16(Bp + b16, lb1);
    Ap += 32;
    Bp += 32;
    __syncthreads();               // compiler drains vmcnt(0) -> LDS valid
    bf16x8_t af[4], bfr[4];
#pragma unroll
    for (int m = 0; m < 4; m++)
      af[m] = *(const bf16x8_t*)&As[(wr + m * 16 + l15) * 32 + lhi * 8];
#pragma unroll
    for (int n = 0; n < 4; n++)
      bfr[n] = *(const bf16x8_t*)&Bs[(wc + n * 16 + l15) * 32 + lhi * 8];
#pragma unroll
    for (int m = 0; m < 4; m++)
#pragma unroll
      for (int n = 0; n < 4; n++)
        acc[m][n] = __builtin_amdgcn_mfma_f32_16x16x32_bf16(af[m], bfr[n],
                                                            acc[m][n], 0, 0, 0);
  }

  void* Cp = C0;
  int rowout = rowbase;
  if (SPLIT3) {
    const int which = rowbase >> 9;  // 4 row-blocks per 512-row output
    Cp = (which == 0) ? C0 : (which == 1) ? C1 : C2;
    rowout = rowbase - which * 512;
  }
  const long cb = (long)bz * sC;
#pragma unroll
  for (int m = 0; m < 4; m++) {
#pragma unroll
    for (int r = 0; r < 4; r++) {
      const int ro = wr + m * 16 + lhi * 4 + r;
      const float bv = BIAS ? bias[rowbase + ro] : 0.0f;
      const long row = rowout + ro;
#pragma unroll
      for (int n = 0; n < 4; n++) {
        const long col = colbase + wc + n * 16 + l15;
        float v = acc[m][n][r] + bv;
        if (RESID) v += resid[(long)bz * sR + row * ldc + col];
        if (OUTBF16)
          ((u16*)Cp)[cb + row * ldc + col] = f2bf(v);
        else
          ((float*)Cp)[cb + row * ldc + col] = v;
      }
    }
  }
}

// ---------------- row softmax over 2304 fp32; writes bf16 P in place ----------
// bf16 P row n lands at u16-offset n*4608 (lda=4608 for the PV GEMM).
__global__ __launch_bounds__(256) void softmax_kernel(float* __restrict__ att) {
  __shared__ float red[8];
  const long rowi = (long)blockIdx.y * 2304 + blockIdx.x;
  const int tid = threadIdx.x;
  const float* p = att + rowi * 2304;
  float v[9];
#pragma unroll
  for (int j = 0; j < 9; j++) v[j] = p[tid + j * 256];
  float m = v[0];
#pragma unroll
  for (int j = 1; j < 9; j++) m = fmaxf(m, v[j]);
#pragma unroll
  for (int o = 32; o; o >>= 1) m = fmaxf(m, __shfl_xor(m, o));
  if ((tid & 63) == 0) red[tid >> 6] = m;
  __syncthreads();
  m = fmaxf(fmaxf(red[0], red[1]), fmaxf(red[2], red[3]));
  float s = 0.0f;
#pragma unroll
  for (int j = 0; j < 9; j++) {
    v[j] = expf(v[j] - m);
    s += v[j];
  }
#pragma unroll
  for (int o = 32; o; o >>= 1) s += __shfl_xor(s, o);
  __syncthreads();
  if ((tid & 63) == 0) red[4 + (tid >> 6)] = s;
  __syncthreads();
  s = (red[4] + red[5]) + (red[6] + red[7]);
  const float inv = 1.0f / s;
  u16* q = (u16*)p;
#pragma unroll
  for (int j = 0; j < 9; j++) q[tid + j * 256] = f2bf(v[j] * inv);
}

extern "C" void kernel_launch(void* const* d_in, const int* in_sizes, int n_in,
                              void* d_out, int out_size, void* d_ws,
                              size_t ws_size, hipStream_t stream) {
  const float* x = (const float*)d_in[0];
  const float* w1 = (const float*)d_in[1];
  const float* b1 = (const float*)d_in[2];
  const float* w2 = (const float*)d_in[3];
  const float* b2 = (const float*)d_in[4];
  const float* w3 = (const float*)d_in[5];
  const float* b3 = (const float*)d_in[6];
  const float* w4 = (const float*)d_in[7];
  const float* b4 = (const float*)d_in[8];
  float* out = (float*)d_out;
  char* ws = (char*)d_ws;

  // B=8, HW=2304, CIN=1024, CMID=512. ws = exactly 256 MiB:
  //  [0,169.87M)  att fp32; before att GEMM this window holds:
  //     [0)       xT      37.75M  (dead after conv GEMM)
  //     [37.75M)  phi_nat 18.87M  (dead after phiT transpose)
  //     [56.62M)  g_nat   18.87M  (dead after gT transpose)
  //     [75.50M)  bcat    6K      (dead after conv GEMM)
  //  [169.87M) wb 4M | theta | phiT | gT | y | yrT  (18.87M each)
  if (ws_size < 268435456ull) return;
  u16* p_xT = (u16*)(ws);
  u16* p_phin = (u16*)(ws + 37748736);
  u16* p_gn = (u16*)(ws + 56623104);
  float* p_bcat = (float*)(ws + 75497472);
  float* p_att = (float*)(ws);
  u16* p_wb = (u16*)(ws + 169869312);
  u16* p_theta = (u16*)(ws + 174063616);
  u16* p_phiT = (u16*)(ws + 192937984);
  u16* p_gT = (u16*)(ws + 211812352);
  u16* p_y = (u16*)(ws + 230686720);
  u16* p_yrT = (u16*)(ws + 249561088);

  // 1) weights -> bf16 ([w1;w2;w3] = [1536,1024] stacked, then w4)
  cast4_kernel<<<dim3(2048, 1, 4), 256, 0, stream>>>(w1, w2, w3, w4, p_wb);
  bcat_kernel<<<dim3(6), 256, 0, stream>>>(b1, b2, b3, p_bcat);
  // 2) xT[b] = cast(x[b])^T : [1024,2304] -> [2304,1024]
  cast_transpose_kernel<<<dim3(72, 32, 8), dim3(32, 8), 0, stream>>>(
      x, p_xT, 1024, 2304, 2359296L, 2359296L);
  // 3) fused theta/phi/g conv: M=1536, N=2304, K=1024
  gemm_glds<true, true, false, true><<<dim3(18, 12, 8), 256, 0, stream>>>(
      p_wb, 1024, 0, p_xT, 1024, 2359296L, p_theta, p_phin, p_gn, 2304,
      1179648L, p_bcat, nullptr, 0, 1024);
  // 4) phiT[m][c] = phi_nat[c][m]; gT[c][m] = (g viewed [2304,512])^T
  transpose_kernel<<<dim3(72, 16, 8), dim3(32, 8), 0, stream>>>(
      p_phin, p_phiT, 512, 2304, 1179648L, 1179648L);
  transpose_kernel<<<dim3(16, 72, 8), dim3(32, 8), 0, stream>>>(
      p_gn, p_gT, 2304, 512, 1179648L, 1179648L);
  // 5) att = theta_v @ phi_v : M=2304, N=2304, K=512, fp32 out
  gemm_glds<false, false, false, false><<<dim3(18, 18, 8), 256, 0, stream>>>(
      p_theta, 512, 1179648L, p_phiT, 512, 1179648L, p_att, nullptr, nullptr,
      2304, 5308416L, nullptr, nullptr, 0, 512);
  // 6) softmax rows -> bf16 P in place (row stride 4608 u16)
  softmax_kernel<<<dim3(2304, 8), 256, 0, stream>>>(p_att);
  // 7) y = P @ g_v : M=2304, N=512, K=2304
  gemm_glds<true, false, false, false><<<dim3(4, 18, 8), 256, 0, stream>>>(
      (const u16*)p_att, 4608, 10616832L, p_gT, 2304, 1179648L, p_y, nullptr,
      nullptr, 512, 1179648L, nullptr, nullptr, 0, 2304);
  // 8) yrT = (y viewed [512,2304])^T
  transpose_kernel<<<dim3(72, 16, 8), dim3(32, 8), 0, stream>>>(
      p_y, p_yrT, 512, 2304, 1179648L, 1179648L);
  // 9) out = x + w4 @ y_r + b4 : M=1024, N=2304, K=512
  gemm_glds<false, true, true, false><<<dim3(18, 8, 8), 256, 0, stream>>>(
      p_wb + 1572864, 512, 0, p_yrT, 512, 1179648L, out, nullptr, nullptr,
      2304, 2359296L, b4, x, 2359296L, 512);
}

// Round 3
// 375.331 us; speedup vs baseline: 1.2053x; 1.1250x over previous
//
#include <hip/hip_runtime.h>

typedef unsigned short u16;
typedef __bf16 bf16x8_t __attribute__((ext_vector_type(8)));
typedef float f32x4_t __attribute__((ext_vector_type(4)));

__device__ __forceinline__ u16 f2bf(float f) {
  unsigned u = __builtin_bit_cast(unsigned, f);
  u += 0x7FFFu + ((u >> 16) & 1u);   // round-to-nearest-even
  return (u16)(u >> 16);
}

typedef __attribute__((address_space(1))) const unsigned gas_u32;
typedef __attribute__((address_space(3))) unsigned las_u32;
__device__ __forceinline__ void gload16(const void* g, void* l) {
  __builtin_amdgcn_global_load_lds((gas_u32*)g, (las_u32*)l, 16, 0, 0);
}

#define SBAR()                                  \
  do {                                          \
    __builtin_amdgcn_sched_barrier(0);          \
    asm volatile("" ::: "memory");              \
    __builtin_amdgcn_s_barrier();               \
    asm volatile("" ::: "memory");              \
    __builtin_amdgcn_sched_barrier(0);          \
  } while (0)
#define VM4() asm volatile("s_waitcnt vmcnt(4)" ::: "memory")

// ---------------- cast the 4 weight matrices fp32->bf16 ----------------------
__global__ __launch_bounds__(256) void cast4_kernel(
    const float* __restrict__ a0, const float* __restrict__ a1,
    const float* __restrict__ a2, const float* __restrict__ a3,
    u16* __restrict__ out) {
  const int z = blockIdx.z;
  const float* a = (z == 0) ? a0 : (z == 1) ? a1 : (z == 2) ? a2 : a3;
  const int i = blockIdx.x * 256 + threadIdx.x;
  out[(size_t)z * 524288 + i] = f2bf(a[i]);
}

// ---------------- concat b1,b2,b3 -> [1536] ----------------------------------
__global__ __launch_bounds__(256) void bcat_kernel(
    const float* __restrict__ b1, const float* __restrict__ b2,
    const float* __restrict__ b3, float* __restrict__ o) {
  const int i = blockIdx.x * 256 + threadIdx.x;
  o[i] = (i < 512) ? b1[i] : (i < 1024) ? b2[i - 512] : b3[i - 1024];
}

// ---------------- fp32 [R,C] -> bf16 [C,R] (batched) --------------------------
__global__ __launch_bounds__(256) void cast_transpose_kernel(
    const float* __restrict__ in, u16* __restrict__ out,
    int R, int C, long sIn, long sOut) {
  __shared__ u16 t[32][33];
  const int b = blockIdx.z;
  in += (long)b * sIn;
  out += (long)b * sOut;
  const int c0 = blockIdx.x * 32, r0 = blockIdx.y * 32;
  const int tx = threadIdx.x, ty = threadIdx.y;
#pragma unroll
  for (int i = 0; i < 32; i += 8)
    t[ty + i][tx] = f2bf(in[(long)(r0 + ty + i) * C + c0 + tx]);
  __syncthreads();
#pragma unroll
  for (int i = 0; i < 32; i += 8)
    out[(long)(c0 + ty + i) * R + r0 + tx] = t[tx][ty + i];
}

// ---------------- bf16 [R,C] -> bf16 [C,R] (batched) --------------------------
__global__ __launch_bounds__(256) void transpose_kernel(
    const u16* __restrict__ in, u16* __restrict__ out,
    int R, int C, long sIn, long sOut) {
  __shared__ u16 t[32][33];
  const int b = blockIdx.z;
  in += (long)b * sIn;
  out += (long)b * sOut;
  const int c0 = blockIdx.x * 32, r0 = blockIdx.y * 32;
  const int tx = threadIdx.x, ty = threadIdx.y;
#pragma unroll
  for (int i = 0; i < 32; i += 8)
    t[ty + i][tx] = in[(long)(r0 + ty + i) * C + c0 + tx];
  __syncthreads();
#pragma unroll
  for (int i = 0; i < 32; i += 8)
    out[(long)(c0 + ty + i) * R + r0 + tx] = t[tx][ty + i];
}

// ---------------- 256x256 8-phase bf16 GEMM: C = A[M,K] * Bt[N,K]^T -----------
// 512 threads = 8 waves (2M x 4N), per-wave 128x64 output (8x4 16x16x32 frags).
// LDS 128 KiB: A/B x 2 buf x [half0|half1] (each half 128 LDS rows x 128B),
// row-permuted so halves are contiguous; k-bytes XOR-swizzled by (lrow&7)<<4
// (pre-swizzled global source feeds linear global_load_lds dests, so both
// sides see the same involution). Phases per K-tile: ph1 reads A0+B0, ph2 B1,
// ph3 A1, ph4 none; one half-tile staged per phase into dead regions;
// vmcnt(4) once per K-tile; raw s_barrier (no vmcnt(0) drain); setprio MFMA.
template <bool OUTBF16, bool BIAS, bool RESID, bool SPLIT3>
__global__ __launch_bounds__(512, 2) void gemm8(
    const u16* __restrict__ A, int lda, long sA,
    const u16* __restrict__ B, int ldb, long sB,
    void* __restrict__ C0, void* __restrict__ C1, void* __restrict__ C2,
    int ldc, long sC, const float* __restrict__ bias,
    const float* __restrict__ resid, long sR, int K) {
  __shared__ alignas(16) char lds[131072];
  const int tid = threadIdx.x;
  const int w = tid >> 6, l = tid & 63;
  const int wr = w >> 2, wc = w & 3;
  const int l15 = l & 15, lhi = l >> 4;
  const int koff0 = (lhi * 16) ^ ((l & 7) << 4);
  const int bz = blockIdx.z;
  const int rowbase = blockIdx.y * 256, colbase = blockIdx.x * 256;

  // staging addresses: slot s = call*512 + tid; sub = s>>3 indexes LDS row
  // within the half; global row/col recovered via the half-permutation.
  const int sub = tid >> 3;  // call-0 sub in [0,64)
  const int kb = ((tid & 7) * 16) ^ ((sub & 7) << 4);
  const char* Ag =
      (const char*)(A + (size_t)bz * sA + (size_t)(rowbase + sub) * lda) + kb;
  const char* Bg =
      (const char*)(B + (size_t)bz * sB +
                    (size_t)(colbase + (sub >> 5) * 64 + (sub & 31)) * ldb) + kb;
  const size_t Ahalf = (size_t)64 * lda * 2, Acall = (size_t)128 * lda * 2;
  const size_t Bhalf = (size_t)32 * ldb * 2, Bcall = (size_t)128 * ldb * 2;
  char* sAd = lds + w * 1024;
  char* sBd = lds + 65536 + w * 1024;

#define STG_A(bufv, h, kt)                                              \
  do {                                                                  \
    const char* g_ = Ag + (size_t)(kt) * 128 + (size_t)(h) * Ahalf;     \
    char* d_ = sAd + (bufv) * 32768 + (h) * 16384;                      \
    gload16(g_, d_);                                                    \
    gload16(g_ + Acall, d_ + 8192);                                     \
  } while (0)
#define STG_B(bufv, h, kt)                                              \
  do {                                                                  \
    const char* g_ = Bg + (size_t)(kt) * 128 + (size_t)(h) * Bhalf;     \
    char* d_ = sBd + (bufv) * 32768 + (h) * 16384;                      \
    gload16(g_, d_);                                                    \
    gload16(g_ + Bcall, d_ + 8192);                                     \
  } while (0)

  f32x4_t acc[8][4] = {};
  bf16x8_t af[4][2], bfr[4][2];

#define LOAD_A(bufv, mh)                                                     \
  _Pragma("unroll") for (int m = 0; m < 4; m++) {                            \
    const int lr_ = (mh)*128 + wr * 64 + m * 16 + l15;                       \
    af[m][0] = *(const bf16x8_t*)(lds + (bufv)*32768 + lr_ * 128 + koff0);   \
    af[m][1] =                                                               \
        *(const bf16x8_t*)(lds + (bufv)*32768 + lr_ * 128 + (koff0 ^ 64));   \
  }
#define LOAD_B(bufv, nh)                                                     \
  _Pragma("unroll") for (int n = 0; n < 2; n++) {                            \
    const int lr_ = (nh)*128 + wc * 32 + n * 16 + l15;                       \
    bfr[(nh)*2 + n][0] =                                                     \
        *(const bf16x8_t*)(lds + 65536 + (bufv)*32768 + lr_ * 128 + koff0);  \
    bfr[(nh)*2 + n][1] = *(const bf16x8_t*)(lds + 65536 + (bufv)*32768 +     \
                                            lr_ * 128 + (koff0 ^ 64));       \
  }
#define MMA(mh, nh)                                                          \
  __builtin_amdgcn_s_setprio(1);                                            \
  _Pragma("unroll") for (int m = 0; m < 4; m++)                              \
      _Pragma("unroll") for (int n = 0; n < 2; n++)                          \
          _Pragma("unroll") for (int kk = 0; kk < 2; kk++)                   \
              acc[(mh)*4 + m][(nh)*2 + n] =                                  \
      __builtin_amdgcn_mfma_f32_16x16x32_bf16(                               \
          af[m][kk], bfr[(nh)*2 + n][kk], acc[(mh)*4 + m][(nh)*2 + n], 0, 0, \
          0);                                                                \
  __builtin_amdgcn_s_setprio(0);

  const int NT = K >> 6;
  // prologue: tile0 fully, tile1 A0/B0; wait so tile0 landed (4 = 2 halves).
  STG_A(0, 0, 0); STG_B(0, 0, 0);
  STG_A(0, 1, 0); STG_B(0, 1, 0);
  STG_A(1, 0, 1); STG_B(1, 0, 1);
  VM4();
  SBAR();

  for (int t = 0; t < NT; ++t) {
    const int c = t & 1;
    const int tn = (t + 1 < NT) ? t + 1 : NT - 1;
    const int tn2 = (t + 2 < NT) ? t + 2 : NT - 1;
    // ph1: read A0+B0 of buf c; stage (t+1).A1 -> buf c^1 (dead since its ph3)
    LOAD_A(c, 0);
    LOAD_B(c, 0);
    STG_A(c ^ 1, 1, tn);
    SBAR();
    MMA(0, 0);
    SBAR();
    // ph2: read B1; stage (t+1).B1 -> buf c^1
    LOAD_B(c, 1);
    STG_B(c ^ 1, 1, tn);
    SBAR();
    MMA(0, 1);
    SBAR();
    // ph3: read A1; stage (t+2).A0 -> buf c (A0 dead since ph1)
    LOAD_A(c, 1);
    STG_A(c, 0, tn2);
    SBAR();
    MMA(1, 0);
    SBAR();
    // ph4: stage (t+2).B0 -> buf c (B0 dead since ph1); counted wait:
    // leaves exactly ph3+ph4's 4 loads in flight -> tile t+1 fully landed.
    STG_B(c, 0, tn2);
    VM4();
    SBAR();
    MMA(1, 1);
    SBAR();
  }

  void* Cp = C0;
  long rowoutbase = rowbase + wr * 128;
  if (SPLIT3) {
    const int which = (rowbase + wr * 128) >> 9;
    Cp = (which == 0) ? C0 : (which == 1) ? C1 : C2;
    rowoutbase = rowbase + wr * 128 - which * 512;
  }
  const long cb = (long)bz * sC;
#pragma unroll
  for (int mf = 0; mf < 8; mf++) {
#pragma unroll
    for (int r = 0; r < 4; r++) {
      const int ro = mf * 16 + lhi * 4 + r;
      const long row = rowoutbase + ro;
      const float bv = BIAS ? bias[rowbase + wr * 128 + ro] : 0.0f;
#pragma unroll
      for (int nf = 0; nf < 4; nf++) {
        const long col = colbase + wc * 64 + nf * 16 + l15;
        float v = acc[mf][nf][r] + bv;
        if (RESID) v += resid[(long)bz * sR + row * ldc + col];
        if (OUTBF16)
          ((u16*)Cp)[cb + row * ldc + col] = f2bf(v);
        else
          ((float*)Cp)[cb + row * ldc + col] = v;
      }
    }
  }
#undef STG_A
#undef STG_B
#undef LOAD_A
#undef LOAD_B
#undef MMA
}

// ---------------- row softmax over 2304 fp32; writes bf16 P in place ----------
// bf16 P row n lands at u16-offset n*4608 (lda=4608 for the PV GEMM).
__global__ __launch_bounds__(256) void softmax_kernel(float* __restrict__ att) {
  __shared__ float red[8];
  const long rowi = (long)blockIdx.y * 2304 + blockIdx.x;
  const int tid = threadIdx.x;
  const float* p = att + rowi * 2304;
  float v[9];
#pragma unroll
  for (int j = 0; j < 9; j++) v[j] = p[tid + j * 256];
  float m = v[0];
#pragma unroll
  for (int j = 1; j < 9; j++) m = fmaxf(m, v[j]);
#pragma unroll
  for (int o = 32; o; o >>= 1) m = fmaxf(m, __shfl_xor(m, o));
  if ((tid & 63) == 0) red[tid >> 6] = m;
  __syncthreads();
  m = fmaxf(fmaxf(red[0], red[1]), fmaxf(red[2], red[3]));
  float s = 0.0f;
#pragma unroll
  for (int j = 0; j < 9; j++) {
    v[j] = expf(v[j] - m);
    s += v[j];
  }
#pragma unroll
  for (int o = 32; o; o >>= 1) s += __shfl_xor(s, o);
  __syncthreads();
  if ((tid & 63) == 0) red[4 + (tid >> 6)] = s;
  __syncthreads();
  s = (red[4] + red[5]) + (red[6] + red[7]);
  const float inv = 1.0f / s;
  u16* q = (u16*)p;
#pragma unroll
  for (int j = 0; j < 9; j++) q[tid + j * 256] = f2bf(v[j] * inv);
}

extern "C" void kernel_launch(void* const* d_in, const int* in_sizes, int n_in,
                              void* d_out, int out_size, void* d_ws,
                              size_t ws_size, hipStream_t stream) {
  const float* x = (const float*)d_in[0];
  const float* w1 = (const float*)d_in[1];
  const float* b1 = (const float*)d_in[2];
  const float* w2 = (const float*)d_in[3];
  const float* b2 = (const float*)d_in[4];
  const float* w3 = (const float*)d_in[5];
  const float* b3 = (const float*)d_in[6];
  const float* w4 = (const float*)d_in[7];
  const float* b4 = (const float*)d_in[8];
  float* out = (float*)d_out;
  char* ws = (char*)d_ws;

  // B=8, HW=2304, CIN=1024, CMID=512. ws = exactly 256 MiB:
  //  [0,169.87M)  att fp32; before the att GEMM this window holds:
  //     [0)       xT      37.75M  (dead after conv GEMM)
  //     [37.75M)  phi_nat 18.87M  (dead after phiT transpose)
  //     [56.62M)  g_nat   18.87M  (dead after gT transpose)
  //     [75.50M)  bcat    6K      (dead after conv GEMM)
  //  [169.87M) wb 4M | theta | phiT | gT | y | yrT  (18.87M each)
  if (ws_size < 268435456ull) return;
  u16* p_xT = (u16*)(ws);
  u16* p_phin = (u16*)(ws + 37748736);
  u16* p_gn = (u16*)(ws + 56623104);
  float* p_bcat = (float*)(ws + 75497472);
  float* p_att = (float*)(ws);
  u16* p_wb = (u16*)(ws + 169869312);
  u16* p_theta = (u16*)(ws + 174063616);
  u16* p_phiT = (u16*)(ws + 192937984);
  u16* p_gT = (u16*)(ws + 211812352);
  u16* p_y = (u16*)(ws + 230686720);
  u16* p_yrT = (u16*)(ws + 249561088);

  // 1) weights -> bf16 ([w1;w2;w3] = [1536,1024] stacked, then w4)
  cast4_kernel<<<dim3(2048, 1, 4), 256, 0, stream>>>(w1, w2, w3, w4, p_wb);
  bcat_kernel<<<dim3(6), 256, 0, stream>>>(b1, b2, b3, p_bcat);
  // 2) xT[b] = cast(x[b])^T : [1024,2304] -> [2304,1024]
  cast_transpose_kernel<<<dim3(72, 32, 8), dim3(32, 8), 0, stream>>>(
      x, p_xT, 1024, 2304, 2359296L, 2359296L);
  // 3) fused theta/phi/g conv: M=1536, N=2304, K=1024
  gemm8<true, true, false, true><<<dim3(9, 6, 8), 512, 0, stream>>>(
      p_wb, 1024, 0, p_xT, 1024, 2359296L, p_theta, p_phin, p_gn, 2304,
      1179648L, p_bcat, nullptr, 0, 1024);
  // 4) phiT[m][c] = phi_nat[c][m]; gT[c][m] = (g viewed [2304,512])^T
  transpose_kernel<<<dim3(72, 16, 8), dim3(32, 8), 0, stream>>>(
      p_phin, p_phiT, 512, 2304, 1179648L, 1179648L);
  transpose_kernel<<<dim3(16, 72, 8), dim3(32, 8), 0, stream>>>(
      p_gn, p_gT, 2304, 512, 1179648L, 1179648L);
  // 5) att = theta_v @ phi_v : M=2304, N=2304, K=512, fp32 out
  gemm8<false, false, false, false><<<dim3(9, 9, 8), 512, 0, stream>>>(
      p_theta, 512, 1179648L, p_phiT, 512, 1179648L, p_att, nullptr, nullptr,
      2304, 5308416L, nullptr, nullptr, 0, 512);
  // 6) softmax rows -> bf16 P in place (row stride 4608 u16)
  softmax_kernel<<<dim3(2304, 8), 256, 0, stream>>>(p_att);
  // 7) y = P @ g_v : M=2304, N=512, K=2304
  gemm8<true, false, false, false><<<dim3(2, 9, 8), 512, 0, stream>>>(
      (const u16*)p_att, 4608, 10616832L, p_gT, 2304, 1179648L, p_y, nullptr,
      nullptr, 512, 1179648L, nullptr, nullptr, 0, 2304);
  // 8) yrT = (y viewed [512,2304])^T
  transpose_kernel<<<dim3(72, 16, 8), dim3(32, 8), 0, stream>>>(
      p_y, p_yrT, 512, 2304, 1179648L, 1179648L);
  // 9) out = x + w4 @ y_r + b4 : M=1024, N=2304, K=512
  gemm8<false, true, true, false><<<dim3(9, 4, 8), 512, 0, stream>>>(
      p_wb + 1572864, 512, 0, p_yrT, 512, 1179648L, out, nullptr, nullptr,
      2304, 2359296L, b4, x, 2359296L, 512);
}

// Round 4
// 337.445 us; speedup vs baseline: 1.3406x; 1.1123x over previous
//
#include <hip/hip_runtime.h>

typedef unsigned short u16;
typedef __bf16 bf16x8_t __attribute__((ext_vector_type(8)));
typedef float f32x4_t __attribute__((ext_vector_type(4)));
typedef _Float16 f16x2 __attribute__((ext_vector_type(2)));

__device__ __forceinline__ u16 f2bf(float f) {
  unsigned u = __builtin_bit_cast(unsigned, f);
  u += 0x7FFFu + ((u >> 16) & 1u);   // round-to-nearest-even
  return (u16)(u >> 16);
}

typedef __attribute__((address_space(1))) const unsigned gas_u32;
typedef __attribute__((address_space(3))) unsigned las_u32;
__device__ __forceinline__ void gload16(const void* g, void* l) {
  __builtin_amdgcn_global_load_lds((gas_u32*)g, (las_u32*)l, 16, 0, 0);
}

#define SBAR()                                  \
  do {                                          \
    __builtin_amdgcn_sched_barrier(0);          \
    asm volatile("" ::: "memory");              \
    __builtin_amdgcn_s_barrier();               \
    asm volatile("" ::: "memory");              \
    __builtin_amdgcn_sched_barrier(0);          \
  } while (0)
#define VM4() asm volatile("s_waitcnt vmcnt(4)" ::: "memory")

// ---------------- cast the 4 weight matrices fp32->bf16 ----------------------
__global__ __launch_bounds__(256) void cast4_kernel(
    const float* __restrict__ a0, const float* __restrict__ a1,
    const float* __restrict__ a2, const float* __restrict__ a3,
    u16* __restrict__ out) {
  const int z = blockIdx.z;
  const float* a = (z == 0) ? a0 : (z == 1) ? a1 : (z == 2) ? a2 : a3;
  const int i = blockIdx.x * 256 + threadIdx.x;
  out[(size_t)z * 524288 + i] = f2bf(a[i]);
}

// ---------------- concat b1,b2,b3 -> [1536] ----------------------------------
__global__ __launch_bounds__(256) void bcat_kernel(
    const float* __restrict__ b1, const float* __restrict__ b2,
    const float* __restrict__ b3, float* __restrict__ o) {
  const int i = blockIdx.x * 256 + threadIdx.x;
  o[i] = (i < 512) ? b1[i] : (i < 1024) ? b2[i - 512] : b3[i - 1024];
}

// ---------------- fp32 [R,C] -> bf16 [C,R] (batched) --------------------------
__global__ __launch_bounds__(256) void cast_transpose_kernel(
    const float* __restrict__ in, u16* __restrict__ out,
    int R, int C, long sIn, long sOut) {
  __shared__ u16 t[32][33];
  const int b = blockIdx.z;
  in += (long)b * sIn;
  out += (long)b * sOut;
  const int c0 = blockIdx.x * 32, r0 = blockIdx.y * 32;
  const int tx = threadIdx.x, ty = threadIdx.y;
#pragma unroll
  for (int i = 0; i < 32; i += 8)
    t[ty + i][tx] = f2bf(in[(long)(r0 + ty + i) * C + c0 + tx]);
  __syncthreads();
#pragma unroll
  for (int i = 0; i < 32; i += 8)
    out[(long)(c0 + ty + i) * R + r0 + tx] = t[tx][ty + i];
}

// ---------------- bf16 [R,C] -> bf16 [C,R] (batched) --------------------------
__global__ __launch_bounds__(256) void transpose_kernel(
    const u16* __restrict__ in, u16* __restrict__ out,
    int R, int C, long sIn, long sOut) {
  __shared__ u16 t[32][33];
  const int b = blockIdx.z;
  in += (long)b * sIn;
  out += (long)b * sOut;
  const int c0 = blockIdx.x * 32, r0 = blockIdx.y * 32;
  const int tx = threadIdx.x, ty = threadIdx.y;
#pragma unroll
  for (int i = 0; i < 32; i += 8)
    t[ty + i][tx] = in[(long)(r0 + ty + i) * C + c0 + tx];
  __syncthreads();
#pragma unroll
  for (int i = 0; i < 32; i += 8)
    out[(long)(c0 + ty + i) * R + r0 + tx] = t[tx][ty + i];
}

// ---------------- 256x256 8-phase bf16 GEMM: C = A[M,K] * Bt[N,K]^T -----------
// 512 threads = 8 waves (2M x 4N), per-wave 128x64 output (8x4 16x16x32 frags).
// LDS 128 KiB, A/B x 2buf x row-permuted halves; reads XOR-swizzled; phases
// ph1:A0+B0 ph2:B1 ph3:A1 ph4:-, one staged half per phase into dead regions,
// vmcnt(4) once per K-tile, raw s_barrier, setprio around MFMA clusters.
// OM: 0 = fp32 out, 1 = bf16 out, 2 = fp16 out.
// XCD swizzle: chunked bijective remap (requires gridDim product % 8 == 0);
// blocks-per-chunk == blocks-per-batch here -> one batch per XCD L2.
template <int OM, bool BIAS, bool RESID, bool SPLIT3>
__global__ __launch_bounds__(512, 2) void gemm8(
    const u16* __restrict__ A, int lda, long sA,
    const u16* __restrict__ B, int ldb, long sB,
    void* __restrict__ C0, void* __restrict__ C1, void* __restrict__ C2,
    int ldc, long sC, const float* __restrict__ bias,
    const float* __restrict__ resid, long sR, int K) {
  __shared__ alignas(16) char lds[131072];
  const int tid = threadIdx.x;
  const int w = tid >> 6, l = tid & 63;
  const int wr = w >> 2, wc = w & 3;
  const int l15 = l & 15, lhi = l >> 4;
  const int koff0 = (lhi * 16) ^ ((l & 7) << 4);

  const unsigned gx = gridDim.x, gy = gridDim.y;
  const unsigned nb = gx * gy * gridDim.z;
  unsigned bid = blockIdx.x + gx * (blockIdx.y + gy * blockIdx.z);
  bid = (bid & 7u) * (nb >> 3) + (bid >> 3);
  const unsigned bx = bid % gx;
  const unsigned t1 = bid / gx;
  const unsigned by = t1 % gy;
  const unsigned bz = t1 / gy;
  const int rowbase = by * 256, colbase = bx * 256;

  const int sub = tid >> 3;  // call-0 sub in [0,64)
  const int kb = ((tid & 7) * 16) ^ ((sub & 7) << 4);
  const char* Ag =
      (const char*)(A + (size_t)bz * sA + (size_t)(rowbase + sub) * lda) + kb;
  const char* Bg =
      (const char*)(B + (size_t)bz * sB +
                    (size_t)(colbase + (sub >> 5) * 64 + (sub & 31)) * ldb) + kb;
  const size_t Ahalf = (size_t)64 * lda * 2, Acall = (size_t)128 * lda * 2;
  const size_t Bhalf = (size_t)32 * ldb * 2, Bcall = (size_t)128 * ldb * 2;
  char* sAd = lds + w * 1024;
  char* sBd = lds + 65536 + w * 1024;

#define STG_A(bufv, h, kt)                                              \
  do {                                                                  \
    const char* g_ = Ag + (size_t)(kt) * 128 + (size_t)(h) * Ahalf;     \
    char* d_ = sAd + (bufv) * 32768 + (h) * 16384;                      \
    gload16(g_, d_);                                                    \
    gload16(g_ + Acall, d_ + 8192);                                     \
  } while (0)
#define STG_B(bufv, h, kt)                                              \
  do {                                                                  \
    const char* g_ = Bg + (size_t)(kt) * 128 + (size_t)(h) * Bhalf;     \
    char* d_ = sBd + (bufv) * 32768 + (h) * 16384;                      \
    gload16(g_, d_);                                                    \
    gload16(g_ + Bcall, d_ + 8192);                                     \
  } while (0)

  f32x4_t acc[8][4] = {};
  bf16x8_t af[4][2], bfr[4][2];

#define LOAD_A(bufv, mh)                                                     \
  _Pragma("unroll") for (int m = 0; m < 4; m++) {                            \
    const int lr_ = (mh)*128 + wr * 64 + m * 16 + l15;                       \
    af[m][0] = *(const bf16x8_t*)(lds + (bufv)*32768 + lr_ * 128 + koff0);   \
    af[m][1] =                                                               \
        *(const bf16x8_t*)(lds + (bufv)*32768 + lr_ * 128 + (koff0 ^ 64));   \
  }
#define LOAD_B(bufv, nh)                                                     \
  _Pragma("unroll") for (int n = 0; n < 2; n++) {                            \
    const int lr_ = (nh)*128 + wc * 32 + n * 16 + l15;                       \
    bfr[(nh)*2 + n][0] =                                                     \
        *(const bf16x8_t*)(lds + 65536 + (bufv)*32768 + lr_ * 128 + koff0);  \
    bfr[(nh)*2 + n][1] = *(const bf16x8_t*)(lds + 65536 + (bufv)*32768 +     \
                                            lr_ * 128 + (koff0 ^ 64));       \
  }
#define MMA(mh, nh)                                                          \
  __builtin_amdgcn_s_setprio(1);                                            \
  _Pragma("unroll") for (int m = 0; m < 4; m++)                              \
      _Pragma("unroll") for (int n = 0; n < 2; n++)                          \
          _Pragma("unroll") for (int kk = 0; kk < 2; kk++)                   \
              acc[(mh)*4 + m][(nh)*2 + n] =                                  \
      __builtin_amdgcn_mfma_f32_16x16x32_bf16(                               \
          af[m][kk], bfr[(nh)*2 + n][kk], acc[(mh)*4 + m][(nh)*2 + n], 0, 0, \
          0);                                                                \
  __builtin_amdgcn_s_setprio(0);

  const int NT = K >> 6;
  STG_A(0, 0, 0); STG_B(0, 0, 0);
  STG_A(0, 1, 0); STG_B(0, 1, 0);
  STG_A(1, 0, 1); STG_B(1, 0, 1);
  VM4();
  SBAR();

  for (int t = 0; t < NT; ++t) {
    const int c = t & 1;
    const int tn = (t + 1 < NT) ? t + 1 : NT - 1;
    const int tn2 = (t + 2 < NT) ? t + 2 : NT - 1;
    LOAD_A(c, 0);
    LOAD_B(c, 0);
    STG_A(c ^ 1, 1, tn);
    SBAR();
    MMA(0, 0);
    SBAR();
    LOAD_B(c, 1);
    STG_B(c ^ 1, 1, tn);
    SBAR();
    MMA(0, 1);
    SBAR();
    LOAD_A(c, 1);
    STG_A(c, 0, tn2);
    SBAR();
    MMA(1, 0);
    SBAR();
    STG_B(c, 0, tn2);
    VM4();
    SBAR();
    MMA(1, 1);
    SBAR();
  }

  void* Cp = C0;
  long rowoutbase = rowbase + wr * 128;
  if (SPLIT3) {
    const int which = (rowbase + wr * 128) >> 9;
    Cp = (which == 0) ? C0 : (which == 1) ? C1 : C2;
    rowoutbase = rowbase + wr * 128 - which * 512;
  }
  const long cb = (long)bz * sC;
#pragma unroll
  for (int mf = 0; mf < 8; mf++) {
#pragma unroll
    for (int r = 0; r < 4; r++) {
      const int ro = mf * 16 + lhi * 4 + r;
      const long row = rowoutbase + ro;
      const float bv = BIAS ? bias[rowbase + wr * 128 + ro] : 0.0f;
#pragma unroll
      for (int nf = 0; nf < 4; nf++) {
        const long col = colbase + wc * 64 + nf * 16 + l15;
        float v = acc[mf][nf][r] + bv;
        if (RESID) v += resid[(long)bz * sR + row * ldc + col];
        if (OM == 1)
          ((u16*)Cp)[cb + row * ldc + col] = f2bf(v);
        else if (OM == 2)
          ((u16*)Cp)[cb + row * ldc + col] =
              __builtin_bit_cast(u16, (_Float16)v);
        else
          ((float*)Cp)[cb + row * ldc + col] = v;
      }
    }
  }
#undef STG_A
#undef STG_B
#undef LOAD_A
#undef LOAD_B
#undef MMA
}

// ---------------- row softmax: fp16 scores in, bf16 P out, in place ----------
// att rows contiguous (2304 elems, 2B each). 2 rows/block, 128 threads/row,
// 9 packed u32 per thread.
__global__ __launch_bounds__(256) void softmax_kernel(u16* __restrict__ att) {
  __shared__ float redm[4], reds[4];
  const int tid = threadIdx.x;
  const int r2 = tid >> 7, tx = tid & 127;
  const long row = (long)blockIdx.y * 2304 + blockIdx.x * 2 + r2;
  unsigned* p = (unsigned*)(att + row * 2304);
  unsigned v[9];
#pragma unroll
  for (int j = 0; j < 9; j++) v[j] = p[tx + j * 128];
  float f[18];
#pragma unroll
  for (int j = 0; j < 9; j++) {
    f16x2 h = __builtin_bit_cast(f16x2, v[j]);
    f[2 * j] = (float)h[0];
    f[2 * j + 1] = (float)h[1];
  }
  float m = f[0];
#pragma unroll
  for (int j = 1; j < 18; j++) m = fmaxf(m, f[j]);
#pragma unroll
  for (int o = 32; o; o >>= 1) m = fmaxf(m, __shfl_xor(m, o));
  if ((tid & 63) == 0) redm[tid >> 6] = m;
  __syncthreads();
  m = fmaxf(redm[r2 * 2], redm[r2 * 2 + 1]);
  float s = 0.0f;
#pragma unroll
  for (int j = 0; j < 18; j++) {
    f[j] = __expf(f[j] - m);
    s += f[j];
  }
#pragma unroll
  for (int o = 32; o; o >>= 1) s += __shfl_xor(s, o);
  if ((tid & 63) == 0) reds[tid >> 6] = s;
  __syncthreads();
  const float inv = 1.0f / (reds[r2 * 2] + reds[r2 * 2 + 1]);
#pragma unroll
  for (int j = 0; j < 9; j++) {
    unsigned lo = f2bf(f[2 * j] * inv);
    unsigned hi = f2bf(f[2 * j + 1] * inv);
    p[tx + j * 128] = lo | (hi << 16);
  }
}

extern "C" void kernel_launch(void* const* d_in, const int* in_sizes, int n_in,
                              void* d_out, int out_size, void* d_ws,
                              size_t ws_size, hipStream_t stream) {
  const float* x = (const float*)d_in[0];
  const float* w1 = (const float*)d_in[1];
  const float* b1 = (const float*)d_in[2];
  const float* w2 = (const float*)d_in[3];
  const float* b2 = (const float*)d_in[4];
  const float* w3 = (const float*)d_in[5];
  const float* b3 = (const float*)d_in[6];
  const float* w4 = (const float*)d_in[7];
  const float* b4 = (const float*)d_in[8];
  float* out = (float*)d_out;
  char* ws = (char*)d_ws;

  // B=8, HW=2304, CIN=1024, CMID=512. ws = exactly 256 MiB:
  //  [0,84.93M)  att (fp16 scores -> bf16 P, 2B/elem); before the att GEMM
  //  this window holds xT(37.75M) | phi_nat(18.87M) | g_nat(18.87M) | bcat(6K),
  //  all dead by att-GEMM time.
  //  [169.87M) wb 4M | theta | phiT | gT | y | yrT  (18.87M each)
  if (ws_size < 268435456ull) return;
  u16* p_xT = (u16*)(ws);
  u16* p_phin = (u16*)(ws + 37748736);
  u16* p_gn = (u16*)(ws + 56623104);
  float* p_bcat = (float*)(ws + 75497472);
  u16* p_att = (u16*)(ws);
  u16* p_wb = (u16*)(ws + 169869312);
  u16* p_theta = (u16*)(ws + 174063616);
  u16* p_phiT = (u16*)(ws + 192937984);
  u16* p_gT = (u16*)(ws + 211812352);
  u16* p_y = (u16*)(ws + 230686720);
  u16* p_yrT = (u16*)(ws + 249561088);

  // 1) weights -> bf16 ([w1;w2;w3] = [1536,1024] stacked, then w4)
  cast4_kernel<<<dim3(2048, 1, 4), 256, 0, stream>>>(w1, w2, w3, w4, p_wb);
  bcat_kernel<<<dim3(6), 256, 0, stream>>>(b1, b2, b3, p_bcat);
  // 2) xT[b] = cast(x[b])^T : [1024,2304] -> [2304,1024]
  cast_transpose_kernel<<<dim3(72, 32, 8), dim3(32, 8), 0, stream>>>(
      x, p_xT, 1024, 2304, 2359296L, 2359296L);
  // 3) fused theta/phi/g conv: M=1536, N=2304, K=1024  (432 blocks, 54/XCD)
  gemm8<1, true, false, true><<<dim3(9, 6, 8), 512, 0, stream>>>(
      p_wb, 1024, 0, p_xT, 1024, 2359296L, p_theta, p_phin, p_gn, 2304,
      1179648L, p_bcat, nullptr, 0, 1024);
  // 4) phiT[m][c] = phi_nat[c][m]; gT[c][m] = (g viewed [2304,512])^T
  transpose_kernel<<<dim3(72, 16, 8), dim3(32, 8), 0, stream>>>(
      p_phin, p_phiT, 512, 2304, 1179648L, 1179648L);
  transpose_kernel<<<dim3(16, 72, 8), dim3(32, 8), 0, stream>>>(
      p_gn, p_gT, 2304, 512, 1179648L, 1179648L);
  // 5) att = theta_v @ phi_v : M=2304, N=2304, K=512, fp16 out (648 blk, 81/XCD)
  gemm8<2, false, false, false><<<dim3(9, 9, 8), 512, 0, stream>>>(
      p_theta, 512, 1179648L, p_phiT, 512, 1179648L, p_att, nullptr, nullptr,
      2304, 5308416L, nullptr, nullptr, 0, 512);
  // 6) softmax rows (fp16 -> bf16 P in place, contiguous lda 2304)
  softmax_kernel<<<dim3(1152, 8), 256, 0, stream>>>(p_att);
  // 7) y = P @ g_v : M=2304, N=512, K=2304  (144 blocks, 18/XCD)
  gemm8<1, false, false, false><<<dim3(2, 9, 8), 512, 0, stream>>>(
      p_att, 2304, 5308416L, p_gT, 2304, 1179648L, p_y, nullptr, nullptr, 512,
      1179648L, nullptr, nullptr, 0, 2304);
  // 8) yrT = (y viewed [512,2304])^T
  transpose_kernel<<<dim3(72, 16, 8), dim3(32, 8), 0, stream>>>(
      p_y, p_yrT, 512, 2304, 1179648L, 1179648L);
  // 9) out = x + w4 @ y_r + b4 : M=1024, N=2304, K=512  (288 blocks, 36/XCD)
  gemm8<0, true, true, false><<<dim3(9, 4, 8), 512, 0, stream>>>(
      p_wb + 1572864, 512, 0, p_yrT, 512, 1179648L, out, nullptr, nullptr,
      2304, 2359296L, b4, x, 2359296L, 512);
}